// Round 5
// baseline (96.646 us; speedup 1.0000x reference)
//
#include <hip/hip_runtime.h>

#define GAMMA 0.3f
#define K2_BLOCKS 1024
#define K2_THREADS 256
#define ROWS 8          // neg rows per block sweep; 1024*8 = 8192 ~= negCount

struct Ctl {
  int posCount;
  int negCount;
  unsigned doneCount;
  unsigned pad;
  double accum;
};

// Kernel 1: score + wave-aggregated compaction (round-1 verified).
//   posS[0..posCount)  = s_j               (target==1)
//   negS[0..negCount)  = s_i + gamma       (target!=1)
__global__ void prep_kernel(const float2* __restrict__ inp,
                            const int* __restrict__ target,
                            float* __restrict__ posS,
                            float* __restrict__ negS,
                            Ctl* ctl, int n) {
  int i = blockIdx.x * blockDim.x + threadIdx.x;
  if (i >= n) return;

  float2 x = inp[i];
  float s = 1.0f / (1.0f + expf(x.x - x.y));   // softmax(x)[1]
  bool isPos = (target[i] == 1);

  unsigned long long act = __ballot(1);
  unsigned long long bal = __ballot(isPos);
  int lane = threadIdx.x & 63;
  unsigned long long lt = (lane == 63) ? 0x7fffffffffffffffull
                                       : ((1ull << lane) - 1ull);
  int nPos = __popcll(bal);
  int nNeg = __popcll(act & ~bal);
  int myPosIdx = __popcll(bal & lt);
  int myNegIdx = __popcll(act & ~bal & lt);

  int basePos = 0, baseNeg = 0;
  if (lane == 0) {
    basePos = atomicAdd(&ctl->posCount, nPos);
    baseNeg = atomicAdd(&ctl->negCount, nNeg);
  }
  basePos = __shfl(basePos, 0);
  baseNeg = __shfl(baseNeg, 0);

  if (isPos) posS[basePos + myPosIdx] = s;
  else       negS[baseNeg + myNegIdx] = s + GAMMA;
}

// Kernel 2: sum over (neg i, pos j) of max(negS[i] - posS[j], 0)^2.
// Block sweeps ROWS negatives (registers); threads stride positives with
// float4 (~32 KB, L1/L2-resident). 4 independent FMA chains per thread.
__global__ __launch_bounds__(K2_THREADS)
void pair_kernel(const float* __restrict__ posS,
                 const float* __restrict__ negS,
                 Ctl* ctl, float* __restrict__ out, int n) {
  const int posCount = ctl->posCount;
  const int negCount = ctl->negCount;

  const float4* P4 = (const float4*)posS;
  const int n4 = posCount >> 2;
  const int tailStart = n4 << 2;

  float a0 = 0.f, a1 = 0.f, a2 = 0.f, a3 = 0.f;

  for (int r0 = blockIdx.x * ROWS; r0 < negCount; r0 += gridDim.x * ROWS) {
    float tn[ROWS];
#pragma unroll
    for (int k = 0; k < ROWS; ++k) {
      int r = r0 + k;
      tn[k] = (r < negCount) ? negS[r] : -1e30f;   // sentinel => contributes 0
    }

    for (int jb = threadIdx.x; jb < n4; jb += K2_THREADS) {
      float4 pb = P4[jb];
#pragma unroll
      for (int k = 0; k < ROWS; ++k) {
        float m0 = fmaxf(tn[k] - pb.x, 0.f); a0 = fmaf(m0, m0, a0);
        float m1 = fmaxf(tn[k] - pb.y, 0.f); a1 = fmaf(m1, m1, a1);
        float m2 = fmaxf(tn[k] - pb.z, 0.f); a2 = fmaf(m2, m2, a2);
        float m3 = fmaxf(tn[k] - pb.w, 0.f); a3 = fmaf(m3, m3, a3);
      }
    }
    // scalar tail (posCount % 4 elements)
    for (int j = tailStart + threadIdx.x; j < posCount; j += K2_THREADS) {
      float p = posS[j];
#pragma unroll
      for (int k = 0; k < ROWS; ++k) {
        float m = fmaxf(tn[k] - p, 0.f);
        a0 = fmaf(m, m, a0);
      }
    }
  }

  float acc = (a0 + a1) + (a2 + a3);

  // wave reduce (64 lanes)
  for (int o = 32; o > 0; o >>= 1) acc += __shfl_down(acc, o);

  __shared__ float red[K2_THREADS / 64];
  const int wid = threadIdx.x >> 6;
  const int lane = threadIdx.x & 63;
  if (lane == 0) red[wid] = acc;
  __syncthreads();

  if (threadIdx.x == 0) {
    float b = red[0] + red[1] + red[2] + red[3];
    atomicAdd(&ctl->accum, (double)b);
    __threadfence();
    unsigned done = atomicAdd(&ctl->doneCount, 1u);
    if (done == gridDim.x - 1) {
      __threadfence();
      double total = atomicAdd(&ctl->accum, 0.0);  // coherent RMW readback
      *out = (float)(total / (double)n);
    }
  }
}

extern "C" void kernel_launch(void* const* d_in, const int* in_sizes, int n_in,
                              void* d_out, int out_size, void* d_ws, size_t ws_size,
                              hipStream_t stream) {
  const float2* inp  = (const float2*)d_in[0]; // [N,2] f32
  const int* target  = (const int*)d_in[1];    // [N] int
  const int n = in_sizes[1];

  float* posS = (float*)d_ws;
  float* negS = posS + n;
  Ctl* ctl    = (Ctl*)(negS + n);   // 8-byte aligned (2*n*4 bytes offset)

  hipMemsetAsync(ctl, 0, sizeof(Ctl), stream);

  int blocks1 = (n + 255) / 256;
  prep_kernel<<<blocks1, 256, 0, stream>>>(inp, target, posS, negS, ctl, n);

  pair_kernel<<<K2_BLOCKS, K2_THREADS, 0, stream>>>(posS, negS, ctl, (float*)d_out, n);
}